// Round 3
// baseline (59.849 us; speedup 1.0000x reference)
//
#include <hip/hip_runtime.h>
#include <hip/hip_bf16.h>

// AdaptiveFourierPositionEncoding — round 3: no LDS, depth-2 register pipeline.
// B=8,S=32768,DIM=128,NB=64. 16384 tiles of 16 tokens, 2048 persistent waves,
// 8 tiles/wave. Per tile: logits[64x16] = W(bf16) x X^T(bf16) via 16x
// mfma_f32_16x16x32_bf16 with W frags resident in VGPRs. B-fragments are
// gathered straight from global into VGPRs (no LDS round trip), 2 tiles in
// flight per wave (3-slot rotation, fully unrolled -> static reg indices).

#define NTOK   (8 * 32768)
#define NTILE  (NTOK / 16)        // 16384
#define NW     2048               // persistent waves
#define TPW    (NTILE / NW)       // 8 tiles per wave

typedef short  bf16x8 __attribute__((ext_vector_type(8)));
typedef float  f32x4  __attribute__((ext_vector_type(4)));

static __device__ __forceinline__ short f2bf(float f) {
    __hip_bfloat16 h = __float2bfloat16(f);   // RNE
    return __builtin_bit_cast(short, h);
}

__global__ __launch_bounds__(256, 2) void afpe_r3(
    const float* __restrict__ x, const int* __restrict__ pos,
    const float* __restrict__ fb, const float* __restrict__ ph,
    const float* __restrict__ aw, const float* __restrict__ ab,
    float* __restrict__ out)
{
    const int lane = threadIdx.x & 63;
    const int gw   = blockIdx.x * 4 + (threadIdx.x >> 6);  // 0..2047
    const int q    = lane >> 4;               // k-group / D-row group
    const int tt   = lane & 15;               // token-in-tile / A-row

    // A fragments: W[64][128] -> bf16, resident whole kernel.
    // A[m][c] elem i = W[16m + tt][q*8 + 32c + i]
    bf16x8 A[4][4];
    #pragma unroll
    for (int m = 0; m < 4; ++m) {
        #pragma unroll
        for (int c = 0; c < 4; ++c) {
            const float* wp = aw + (size_t)(16 * m + tt) * 128 + q * 8 + 32 * c;
            const float4 w0 = *(const float4*)wp;
            const float4 w1 = *(const float4*)(wp + 4);
            bf16x8 a;
            a[0] = f2bf(w0.x); a[1] = f2bf(w0.y); a[2] = f2bf(w0.z); a[3] = f2bf(w0.w);
            a[4] = f2bf(w1.x); a[5] = f2bf(w1.y); a[6] = f2bf(w1.z); a[7] = f2bf(w1.w);
            A[m][c] = a;
        }
    }
    // per-lane band params: bands q*4 + 16m + r (r=0..3)
    float4 fbv[4], phv[4], abv[4];
    #pragma unroll
    for (int m = 0; m < 4; ++m) {
        fbv[m] = *(const float4*)(fb + q * 4 + 16 * m);
        phv[m] = *(const float4*)(ph + q * 4 + 16 * m);
        abv[m] = *(const float4*)(ab + q * 4 + 16 * m);
    }

    // 3-slot tile pipeline: xf[s][2c+h] = x[tile][tt][q*8+32c+4h .. +3]
    float4 xf[3][8];
    int    pp[3];

    // prologue: tiles t0, t0+NW
    #pragma unroll
    for (int s = 0; s < 2; ++s) {
        const int t = gw + s * NW;
        const float* base = x + (size_t)t * 2048 + tt * 128 + q * 8;
        #pragma unroll
        for (int c = 0; c < 4; ++c) {
            xf[s][2 * c]     = *(const float4*)(base + 32 * c);
            xf[s][2 * c + 1] = *(const float4*)(base + 32 * c + 4);
        }
        pp[s] = pos[t * 16 + tt];
    }

    #pragma unroll
    for (int it = 0; it < TPW; ++it) {
        const int cur = it % 3;
        const int nxt = (it + 2) % 3;
        const int tile = gw + it * NW;

        // issue tile t+2 loads (clamped re-load of current tile past the end;
        // values unused)
        {
            int lt = tile + 2 * NW;
            if (lt >= NTILE) lt = tile;
            const float* base = x + (size_t)lt * 2048 + tt * 128 + q * 8;
            #pragma unroll
            for (int c = 0; c < 4; ++c) {
                xf[nxt][2 * c]     = *(const float4*)(base + 32 * c);
                xf[nxt][2 * c + 1] = *(const float4*)(base + 32 * c + 4);
            }
            pp[nxt] = pos[lt * 16 + tt];
        }

        // bf16 B fragments from current tile
        bf16x8 B[4];
        #pragma unroll
        for (int c = 0; c < 4; ++c) {
            const float4 b0 = xf[cur][2 * c], b1 = xf[cur][2 * c + 1];
            bf16x8 bv;
            bv[0] = f2bf(b0.x); bv[1] = f2bf(b0.y); bv[2] = f2bf(b0.z); bv[3] = f2bf(b0.w);
            bv[4] = f2bf(b1.x); bv[5] = f2bf(b1.y); bv[6] = f2bf(b1.z); bv[7] = f2bf(b1.w);
            B[c] = bv;
        }

        // logits: acc[m] reg r = logit[band 16m + q*4 + r][token tt]
        f32x4 acc[4];
        #pragma unroll
        for (int m = 0; m < 4; ++m) {
            acc[m][0] = abv[m].x; acc[m][1] = abv[m].y;
            acc[m][2] = abv[m].z; acc[m][3] = abv[m].w;
        }
        #pragma unroll
        for (int c = 0; c < 4; ++c) {
            #pragma unroll
            for (int m = 0; m < 4; ++m)
                acc[m] = __builtin_amdgcn_mfma_f32_16x16x32_bf16(A[m][c], B[c], acc[m], 0, 0, 0);
        }

        // softmax over 64 bands of token tt (lanes tt, tt+16, tt+32, tt+48)
        float e[4][4];
        float s = 0.f;
        #pragma unroll
        for (int m = 0; m < 4; ++m) {
            #pragma unroll
            for (int r = 0; r < 4; ++r) { e[m][r] = __expf(acc[m][r]); s += e[m][r]; }
        }
        s += __shfl_xor(s, 16, 64);
        s += __shfl_xor(s, 32, 64);
        const float rinv = 1.0f / s;

        // trig: f32 angle exactly as reference, f64 range-reduce to revolutions
        const float pf = (float)pp[cur];
        float sa[4][4], ca[4][4];
        #pragma unroll
        for (int m = 0; m < 4; ++m) {
            const float fq[4] = {fbv[m].x, fbv[m].y, fbv[m].z, fbv[m].w};
            const float pq[4] = {phv[m].x, phv[m].y, phv[m].z, phv[m].w};
            #pragma unroll
            for (int r = 0; r < 4; ++r) {
                float ang = pf * fq[r];
                ang = ang + pq[r];
                double td = (double)ang * 0.15915494309189535;  // 1/(2*pi)
                td -= floor(td);
                const float rev = (float)td;
                const float at  = e[m][r] * rinv;
                sa[m][r] = __builtin_amdgcn_sinf(rev) * at;
                ca[m][r] = __builtin_amdgcn_cosf(rev) * at;
            }
        }

        // out[tt][k] = x + {sin,cos}*attn ; chunk c's bands == acc[c]'s bands
        float* ob = out + (size_t)(tile * 16 + tt) * 128 + q * 8;
        #pragma unroll
        for (int c = 0; c < 4; ++c) {
            #pragma unroll
            for (int h = 0; h < 2; ++h) {
                const float4 xv = xf[cur][2 * c + h];
                float4 o;
                o.x = xv.x + sa[c][2 * h];
                o.y = xv.y + ca[c][2 * h];
                o.z = xv.z + sa[c][2 * h + 1];
                o.w = xv.w + ca[c][2 * h + 1];
                *(float4*)(ob + 32 * c + 4 * h) = o;
            }
        }
    }
}

extern "C" void kernel_launch(void* const* d_in, const int* in_sizes, int n_in,
                              void* d_out, int out_size, void* d_ws, size_t ws_size,
                              hipStream_t stream) {
    const float* x   = (const float*)d_in[0];
    const int*   pos = (const int*)d_in[1];
    const float* fb  = (const float*)d_in[2];
    const float* ph  = (const float*)d_in[3];
    const float* aw  = (const float*)d_in[4];
    const float* ab  = (const float*)d_in[5];
    float* out = (float*)d_out;

    // 512 blocks x 4 waves = 2048 persistent waves; 8 tiles (128 tokens) each.
    afpe_r3<<<512, 256, 0, stream>>>(x, pos, fb, ph, aw, ab, out);
}